// Round 10
// baseline (190.114 us; speedup 1.0000x reference)
//
#include <hip/hip_runtime.h>

typedef unsigned int u32;
typedef unsigned long long u64;

#define NBATCH 8
#define NPTS   4096
#define NQTOT  (NBATCH * NPTS)   /* 32768 */
#define KNN    16
#define NBASIS 8
#define OUTM   64
#define NSPLIT 8
#define WIN    (NPTS / NSPLIT)   /* 512 candidates per window */
#define QPB    64
#define TKNN   (QPB * NSPLIT)    /* 512 threads = 8 waves */
#define GRP    16
#define BUFCAP 64
/* per-query LDS row: 64 funnel slots + 16 t16 slots + 1 pad */
#define ROWSTR 81
#define TOFF   64
/* screening margin: covers worst-case |(q2+2hc-2s) - d2_exact| (~2e-5) */
#define MARGIN 1e-4f

// sentinel: d2 = +inf, idx = all-ones (sorts last)
#define SENT 0x7f800000ffffffffull

__device__ __forceinline__ void ce(u64& x, u64& y) {
  u64 a = x, b = y;
  bool sw = b < a;
  x = sw ? b : a;
  y = sw ? a : b;
}

// Batcher odd-even mergesort network (fully unrolled).
template <int N>
__device__ __forceinline__ void oems_sort(u64* a) {
#pragma unroll
  for (int p = 1; p < N; p <<= 1) {
#pragma unroll
    for (int k = p; k >= 1; k >>= 1) {
#pragma unroll
      for (int j = k & (p - 1); j + k < N; j += 2 * k) {
#pragma unroll
        for (int i = 0; i < k; ++i) {
          int lo = i + j, hi = i + j + k;
          if (hi < N && (lo / (2 * p)) == (hi / (2 * p)))
            ce(a[lo], a[hi]);
        }
      }
    }
  }
}

// t, a sorted asc -> t = smallest 16 of union, sorted asc.
__device__ __forceinline__ void merge16(u64 t[16], const u64 a[16]) {
  u64 m[16];
#pragma unroll
  for (int i = 0; i < 16; ++i) {
    u64 x = t[i], y = a[15 - i];
    m[i] = (x < y) ? x : y;
  }
#pragma unroll
  for (int k = 8; k >= 1; k >>= 1) {
#pragma unroll
    for (int i = 0; i < 16; ++i) {
      if ((i & k) == 0) ce(m[i], m[i | k]);
    }
  }
#pragma unroll
  for (int i = 0; i < 16; ++i) t[i] = m[i];
}

// Bit-exact d2 vs reference: separate mul/add, ((x+y)+z), no contraction.
__device__ __forceinline__ float d2exact(float qx, float qy, float qz,
                                         float cx, float cy, float cz) {
  float dx = __fadd_rn(qx, -cx);
  float dy = __fadd_rn(qy, -cy);
  float dz = __fadd_rn(qz, -cz);
  return __fadd_rn(__fadd_rn(__fmul_rn(dx, dx), __fmul_rn(dy, dy)),
                   __fmul_rn(dz, dz));
}

// Fused kNN + tensor-product features. Funnel structure (R9) with
// dot-product screening: d2 = q2 + 2*hc - 2*(q.c), hc precomputed in cpad.w.
// Screen with conservative margin (cheap FMA path, wave-uniform SGPR loads);
// recompute BIT-EXACT d2 only on the rare append path. Funnel keys stay
// bit-identical to the reference -> same top-16, same tie-breaks.
// NO __launch_bounds__ min-waves: forcing VGPR down spills (R7: +48MB HBM).
__global__ __launch_bounds__(TKNN) void se3_kernel(
    const float4* __restrict__ cpad, const float* __restrict__ Wmat,
    float* __restrict__ out) {
  __shared__ u64 sBuf[QPB * ROWSTR];  // 41.5 KB: funnel + t16 per query row
  __shared__ u32 sCnt[QPB];
  __shared__ float sThr[QPB];
  __shared__ float sM[QPB * 25];      // reduced M[8][3], stride 25

  const int b = blockIdx.x;
  const int qg = blockIdx.y;
  const int tid = threadIdx.x;
  const int ql = tid & 63;
  const int sp = tid >> 6;  // window id, wave-uniform
  const int qi = qg * QPB + ql;
  const int base = b * NPTS;

  if (tid < QPB) sCnt[tid] = 0;

  // per-lane query coords (coalesced float4)
  const float4 qv = cpad[base + qi];
  const float qx = qv.x, qy = qv.y, qz = qv.z;
  const float q2 = 2.0f * qv.w;  // |q|^2 (rounded; covered by MARGIN)

  // wave-uniform candidate window -> scalar (SGPR) float4 loads
  const int wbase = __builtin_amdgcn_readfirstlane(sp * WIN);
  const float4* cp4 = cpad + base + wbase;
  const int sj = qi - wbase;  // self position inside window (may be OOR)

  // ---- Seed: every thread sorts its window's first 16 candidates ----
  {
    u64 s16[16];
#pragma unroll
    for (int i = 0; i < 16; ++i) {
      float4 c = cp4[i];
      float d2 = d2exact(qx, qy, qz, c.x, c.y, c.z);
      u64 v = ((u64)__float_as_uint(d2) << 32) | (u32)(wbase + i);
      s16[i] = (i == sj) ? SENT : v;
    }
    oems_sort<16>(s16);

    // Round A: waves 1..4 publish pre-sorted lists into funnel slots.
    if (sp >= 1 && sp <= 4) {
#pragma unroll
      for (int e = 0; e < 16; ++e)
        sBuf[ql * ROWSTR + (sp - 1) * 16 + e] = s16[e];
    }
    __syncthreads();
    if (sp == 0) {
      u64 t16[16];
#pragma unroll
      for (int e = 0; e < 16; ++e) t16[e] = s16[e];
#pragma unroll
      for (int s = 0; s < 4; ++s) {
        u64 a[16];
#pragma unroll
        for (int e = 0; e < 16; ++e) a[e] = sBuf[ql * ROWSTR + s * 16 + e];
        merge16(t16, a);
      }
#pragma unroll
      for (int e = 0; e < 16; ++e) sBuf[ql * ROWSTR + TOFF + e] = t16[e];
    }
    __syncthreads();
    // Round B: waves 5..7 publish.
    if (sp >= 5) {
#pragma unroll
      for (int e = 0; e < 16; ++e)
        sBuf[ql * ROWSTR + (sp - 5) * 16 + e] = s16[e];
    }
    __syncthreads();
    if (sp == 0) {
      u64 t16[16];
#pragma unroll
      for (int e = 0; e < 16; ++e) t16[e] = sBuf[ql * ROWSTR + TOFF + e];
#pragma unroll
      for (int s = 0; s < 3; ++s) {
        u64 a[16];
#pragma unroll
        for (int e = 0; e < 16; ++e) a[e] = sBuf[ql * ROWSTR + s * 16 + e];
        merge16(t16, a);
      }
#pragma unroll
      for (int e = 0; e < 16; ++e) sBuf[ql * ROWSTR + TOFF + e] = t16[e];
      sThr[ql] = __uint_as_float((u32)(t16[15] >> 32));
    }
    __syncthreads();
  }
  float thr = sThr[ql];
  float Kq = 0.5f * (q2 - thr - MARGIN);  // screen: s >= Kq + hc

  // ---- Main scan: doubling phases; digest wave rotates (1..5) ----
#pragma unroll
  for (int ph = 0; ph < 5; ++ph) {
    const int cstart = 16 << ph;  // [16,32),[32,64),...,[256,512)
    const int cend = 32 << ph;
    for (int g = cstart; g < cend; g += GRP) {
      // wave-uniform base: 4x s_load_dwordx16 worth of candidates
      float sv[GRP];
      float4 cc[GRP];
      u64 anyG = 0;
#pragma unroll
      for (int i = 0; i < GRP; ++i) {
        float4 c = cp4[g + i];
        cc[i] = c;
        // screening dot: 3 FMA (one SGPR operand each)
        float s = __builtin_fmaf(qx, c.x,
                  __builtin_fmaf(qy, c.y, qz * c.z));
        sv[i] = s;
        anyG |= __ballot(s >= Kq + c.w);
      }
      if (anyG) {  // rare: some lane wants some candidate in this group
#pragma unroll
        for (int i = 0; i < GRP; ++i) {
          if (__any(sv[i] >= Kq + cc[i].w)) {
            float d2 = d2exact(qx, qy, qz, cc[i].x, cc[i].y, cc[i].z);
            int j = wbase + g + i;
            if (d2 <= thr && j != qi) {  // exact test: append iff true cand
              u32 slot = atomicAdd(&sCnt[ql], 1u);
              if (slot < BUFCAP)
                sBuf[ql * ROWSTR + slot] =
                    ((u64)__float_as_uint(d2) << 32) | (u32)j;
            }
          }
        }
      }
    }
    __syncthreads();
    if (sp == ph + 1) {  // rotating digest wave (1..5)
      int n = (int)sCnt[ql];
      n = n < BUFCAP ? n : BUFCAP;
      if (__any(n > 0)) {
        u64 t16[16];
#pragma unroll
        for (int e = 0; e < 16; ++e) t16[e] = sBuf[ql * ROWSTR + TOFF + e];
        for (int k = 0; __any(k < n); k += 16) {
          u64 a[16];
#pragma unroll
          for (int e = 0; e < 16; ++e)
            a[e] = (k + e < n) ? sBuf[ql * ROWSTR + k + e] : SENT;
          oems_sort<16>(a);
          merge16(t16, a);
        }
#pragma unroll
        for (int e = 0; e < 16; ++e) sBuf[ql * ROWSTR + TOFF + e] = t16[e];
        sThr[ql] = __uint_as_float((u32)(t16[15] >> 32));
      }
      sCnt[ql] = 0;
    }
    __syncthreads();
    thr = sThr[ql];
    Kq = 0.5f * (q2 - thr - MARGIN);
  }

  // ---- Epilogue phase 1 (waves 0-3): partial M over 4 neighbors each ----
  if (sp < 4) {
    const int k = sp;
    u64 pv[4];
#pragma unroll
    for (int e = 0; e < 4; ++e)
      pv[e] = sBuf[ql * ROWSTR + TOFF + k * 4 + e];
    float4 nc[4];
    float dd[4];
#pragma unroll
    for (int e = 0; e < 4; ++e) {
      nc[e] = cpad[base + (int)(u32)pv[e]];  // independent gathers
      dd[e] = __uint_as_float((u32)(pv[e] >> 32));
    }
    float M[24];
#pragma unroll
    for (int j = 0; j < 24; ++j) M[j] = 0.f;
#pragma unroll
    for (int e = 0; e < 4; ++e) {
      float rx = nc[e].x - qx;  // sender - receiver
      float ry = nc[e].y - qy;
      float rz = nc[e].z - qz;
      float dist = sqrtf(dd[e]);
      float inv = 1.0f / (dist + 1e-8f);
      rx *= inv; ry *= inv; rz *= inv;
      float cut = fminf(dist * 0.1f, 1.0f);
      float g[NBASIS], s = 0.f;
#pragma unroll
      for (int v = 0; v < NBASIS; ++v) {
        float t = cut - (float)v * (1.0f / 7.0f);
        g[v] = __expf(-32.0f * t * t);  // sigma = 1/8 -> 1/(2s^2) = 32
        s += g[v];
      }
      float rs = 1.0f / s;
#pragma unroll
      for (int v = 0; v < NBASIS; ++v) {
        float rb = g[v] * rs;
        M[v * 3 + 0] = fmaf(rb, rx, M[v * 3 + 0]);
        M[v * 3 + 1] = fmaf(rb, ry, M[v * 3 + 1]);
        M[v * 3 + 2] = fmaf(rb, rz, M[v * 3 + 2]);
      }
    }
    float* fp = (float*)(sBuf + ql * ROWSTR);
#pragma unroll
    for (int c = 0; c < 24; ++c) fp[k * 25 + c] = M[c];
  }
  __syncthreads();

  // ---- Reduce partials: thread (q = ql, comps sp*3..sp*3+2) ----
  {
    const float* fp = (const float*)(sBuf + ql * ROWSTR);
#pragma unroll
    for (int j0 = 0; j0 < 3; ++j0) {
      int j = sp * 3 + j0;
      float s = fp[0 * 25 + j] + fp[1 * 25 + j] + fp[2 * 25 + j] +
                fp[3 * 25 + j];
      sM[ql * 25 + j] = s;
    }
  }
  __syncthreads();

  // ---- Epilogue phase 2 (all waves): out[q][w*3+m], lane w = ql ----
  float wreg[NBASIS];
#pragma unroll
  for (int v = 0; v < NBASIS; ++v) wreg[v] = Wmat[v * OUTM + ql];
  const float scale = 0.022097086912079608f;  // (1/sqrt(8)) / 16
#pragma unroll
  for (int i = 0; i < 8; ++i) {
    int q = sp * 8 + i;  // wave-uniform -> sM broadcasts
    const float* mq = sM + q * 25;
    float a0 = 0.f, a1 = 0.f, a2 = 0.f;
#pragma unroll
    for (int v = 0; v < NBASIS; ++v) {
      a0 = fmaf(wreg[v], mq[v * 3 + 0], a0);
      a1 = fmaf(wreg[v], mq[v * 3 + 1], a1);
      a2 = fmaf(wreg[v], mq[v * 3 + 2], a2);
    }
    size_t o = (size_t)(base + qg * QPB + q) * (OUTM * 3) + ql * 3;
    out[o + 0] = a0 * scale;
    out[o + 1] = a1 * scale;
    out[o + 2] = a2 * scale;
  }
}

// coords [B*N][3] -> float4 (x,y,z, hc=|c|^2/2).
__global__ void prep_kernel(const float* __restrict__ coords,
                            float4* __restrict__ cpad) {
  int i = blockIdx.x * 256 + threadIdx.x;
  if (i < NQTOT) {
    float x = coords[3 * i + 0];
    float y = coords[3 * i + 1];
    float z = coords[3 * i + 2];
    float hc = 0.5f * (x * x + y * y + z * z);
    cpad[i] = make_float4(x, y, z, hc);
  }
}

extern "C" void kernel_launch(void* const* d_in, const int* in_sizes, int n_in,
                              void* d_out, int out_size, void* d_ws, size_t ws_size,
                              hipStream_t stream) {
  const float* coords = (const float*)d_in[0];
  const float* Wmat = (const float*)d_in[1];
  float* out = (float*)d_out;

  float4* cpad = (float4*)d_ws;  // 512 KB

  prep_kernel<<<dim3((NQTOT + 255) / 256), dim3(256), 0, stream>>>(coords, cpad);
  se3_kernel<<<dim3(NBATCH, NPTS / QPB), dim3(TKNN), 0, stream>>>(cpad, Wmat, out);
}